// Round 1
// baseline (611.966 us; speedup 1.0000x reference)
//
#include <hip/hip_runtime.h>
#include <hip/hip_bf16.h>

#define BB 4
#define LL 2048
#define CC 1024
#define HH 16
#define DD 64
#define HALFD 32

typedef short bf16x8 __attribute__((ext_vector_type(8)));
typedef float f32x4 __attribute__((ext_vector_type(4)));

__device__ __forceinline__ float bf2f(unsigned short u) {
    union { unsigned int i; float f; } x; x.i = ((unsigned int)u) << 16; return x.f;
}
__device__ __forceinline__ unsigned short f2bf(float f) {
    union { float f; unsigned int i; } x; x.f = f;
    return (unsigned short)((x.i + 0x7fffu + ((x.i >> 16) & 1u)) >> 16);
}

// ---------------- prep: fp32 -> bf16 ----------------
__global__ void k_f2bf(const float4* __restrict__ in, ushort4* __restrict__ out, int n4) {
    int i = blockIdx.x * blockDim.x + threadIdx.x;
    if (i < n4) {
        float4 v = in[i];
        ushort4 o;
        o.x = f2bf(v.x); o.y = f2bf(v.y); o.z = f2bf(v.z); o.w = f2bf(v.w);
        out[i] = o;
    }
}

__global__ void k_biascat(const float* __restrict__ qb, const float* __restrict__ vb,
                          float* __restrict__ out) {
    int i = blockIdx.x * blockDim.x + threadIdx.x;
    if (i < 3 * CC) out[i] = (i < CC) ? qb[i] : (i < 2 * CC ? 0.f : vb[i - 2 * CC]);
}

// ---------------- GEMM: C[M,N] = A[M,K] * Bt[N,K]^T + bias[N] ----------------
// 128x128 tile, BK=32, 4 waves (2x2), each wave 64x64 = 4x4 frags of 16x16x32 MFMA.
template <typename OutT>
__global__ __launch_bounds__(256) void k_gemm_bt(
    const unsigned short* __restrict__ A, const unsigned short* __restrict__ Bt,
    const float* __restrict__ bias, OutT* __restrict__ Cout, int M, int N, int K) {
    __shared__ unsigned short As[128][40];  // row stride 80B = 5*16B -> conflict-free-ish b128
    __shared__ unsigned short Bs[128][40];
    int nT = N >> 7;
    int tM = (blockIdx.x / nT) << 7;
    int tN = (blockIdx.x % nT) << 7;
    int t = threadIdx.x;
    int lane = t & 63, wid = t >> 6;
    int wr = (wid >> 1) * 64, wc = (wid & 1) * 64;
    int c = lane & 15, g = lane >> 4;
    f32x4 acc[4][4];
#pragma unroll
    for (int i = 0; i < 4; i++)
#pragma unroll
        for (int j = 0; j < 4; j++) acc[i][j] = (f32x4){0.f, 0.f, 0.f, 0.f};

    for (int k0 = 0; k0 < K; k0 += 32) {
        __syncthreads();
#pragma unroll
        for (int i = t; i < 512; i += 256) {
            int row = i >> 2, ch = (i & 3) << 3;
            *(bf16x8*)&As[row][ch] = *(const bf16x8*)&A[(size_t)(tM + row) * K + k0 + ch];
            *(bf16x8*)&Bs[row][ch] = *(const bf16x8*)&Bt[(size_t)(tN + row) * K + k0 + ch];
        }
        __syncthreads();
        bf16x8 af[4], bfr[4];
#pragma unroll
        for (int fm = 0; fm < 4; fm++) af[fm] = *(const bf16x8*)&As[wr + fm * 16 + c][g * 8];
#pragma unroll
        for (int fn = 0; fn < 4; fn++) bfr[fn] = *(const bf16x8*)&Bs[wc + fn * 16 + c][g * 8];
#pragma unroll
        for (int fm = 0; fm < 4; fm++)
#pragma unroll
            for (int fn = 0; fn < 4; fn++)
                acc[fm][fn] = __builtin_amdgcn_mfma_f32_16x16x32_bf16(af[fm], bfr[fn],
                                                                      acc[fm][fn], 0, 0, 0);
    }
#pragma unroll
    for (int fm = 0; fm < 4; fm++) {
#pragma unroll
        for (int fn = 0; fn < 4; fn++) {
            int col = tN + wc + fn * 16 + c;
            float bv = bias[col];
#pragma unroll
            for (int r = 0; r < 4; r++) {
                int row = tM + wr + fm * 16 + g * 4 + r;
                float v = acc[fm][fn][r] + bv;
                if constexpr (sizeof(OutT) == 2)
                    Cout[(size_t)row * N + col] = f2bf(v);
                else
                    Cout[(size_t)row * N + col] = v;
            }
        }
    }
}

// ---------------- Q/K: l2norm + scale + RoPE, layout (B,H,L,D) bf16 ----------------
__global__ __launch_bounds__(256) void k_qknorm(
    const unsigned short* __restrict__ qkv, const float* __restrict__ rope,
    const float* __restrict__ smul, unsigned short* __restrict__ Q,
    unsigned short* __restrict__ Ko) {
    int wid = threadIdx.x >> 6, lane = threadIdx.x & 63;
    long rowid = (long)blockIdx.x * 4 + wid;  // (b,l,h), h fastest
    int h = rowid & 15;
    long t2 = rowid >> 4;
    int l = t2 & 2047;
    int b = (int)(t2 >> 11);
    size_t base = ((size_t)(b * LL + l) * 3) * CC + h * 64 + lane;
    float q = bf2f(qkv[base]);
    float k = bf2f(qkv[base + CC]);
    float sq = q * q, sk = k * k;
#pragma unroll
    for (int m = 32; m >= 1; m >>= 1) {
        sq += __shfl_xor(sq, m);
        sk += __shfl_xor(sk, m);
    }
    float sm = expf(fminf(smul[h], 4.6051701859880913680f));
    q = q / fmaxf(sqrtf(sq), 1e-12f) * sm;
    k = k / fmaxf(sqrtf(sk), 1e-12f);
    int j = lane >> 1;
    float cs = rope[((size_t)(b * 2) * LL + l) * HALFD + j];
    float sn = rope[((size_t)(b * 2 + 1) * LL + l) * HALFD + j];
    float qp = __shfl_xor(q, 1), kp = __shfl_xor(k, 1);
    float qn = (lane & 1) ? (qp * sn + q * cs) : (q * cs - qp * sn);
    float kn = (lane & 1) ? (kp * sn + k * cs) : (k * cs - kp * sn);
    size_t ob = ((size_t)(b * HH + h) * LL + l) * 64 + lane;
    Q[ob] = f2bf(qn);
    Ko[ob] = f2bf(kn);
}

// ---------------- V transpose: (B,L,H,D) slice of qkv -> Vt (B,H,D,L) bf16 ----------------
__global__ __launch_bounds__(256) void k_vtrans(const unsigned short* __restrict__ qkv,
                                               unsigned short* __restrict__ Vt) {
    __shared__ unsigned short tile[64][65];
    int bid = blockIdx.x;
    int lb = bid & 31;  // L/64
    int bh = bid >> 5;
    int h = bh & 15, b = bh >> 4;
    int t = threadIdx.x;
    for (int i = t; i < 4096; i += 256) {
        int row = i >> 6, dd = i & 63;
        tile[row][dd] = qkv[((size_t)(b * LL + lb * 64 + row) * 3 + 2) * CC + h * 64 + dd];
    }
    __syncthreads();
    for (int i = t; i < 4096; i += 256) {
        int dd = i >> 6, l2 = i & 63;
        Vt[((size_t)bh * 64 + dd) * LL + lb * 64 + l2] = tile[l2][dd];
    }
}

// ---------------- causal flash attention ----------------
// block 256 = 4 waves; each wave: 16 q rows; K-tile 32; MFMA 16x16x32.
__global__ __launch_bounds__(256) void k_attn(
    const unsigned short* __restrict__ Q, const unsigned short* __restrict__ K,
    const unsigned short* __restrict__ Vt, unsigned short* __restrict__ Out) {
    __shared__ unsigned short Pl[4][16][40];
    int wid = threadIdx.x >> 6, lane = threadIdx.x & 63;
    int c = lane & 15, g = lane >> 4;
    int bid = blockIdx.x;
    int qblk = bid & 31;  // L/64
    int bh = bid >> 5;
    int qbase = qblk * 64 + wid * 16;
    const unsigned short* Qh = Q + (size_t)bh * LL * 64;
    const unsigned short* Kh = K + (size_t)bh * LL * 64;
    const unsigned short* Vh = Vt + (size_t)bh * 64 * LL;

    bf16x8 qf0 = *(const bf16x8*)&Qh[(size_t)(qbase + c) * 64 + g * 8];
    bf16x8 qf1 = *(const bf16x8*)&Qh[(size_t)(qbase + c) * 64 + 32 + g * 8];

    f32x4 acc[4];
#pragma unroll
    for (int nc = 0; nc < 4; nc++) acc[nc] = (f32x4){0.f, 0.f, 0.f, 0.f};
    float m_[4] = {-1e30f, -1e30f, -1e30f, -1e30f};
    float l_[4] = {0.f, 0.f, 0.f, 0.f};

    int kend = qbase + 16;
    for (int kt = 0; kt < kend; kt += 32) {
        bool p1 = (kt + 16) < kend;
        f32x4 s0 = (f32x4){0.f, 0.f, 0.f, 0.f}, s1 = (f32x4){0.f, 0.f, 0.f, 0.f};
        {
            bf16x8 ka = *(const bf16x8*)&Kh[(size_t)(kt + c) * 64 + g * 8];
            bf16x8 kb = *(const bf16x8*)&Kh[(size_t)(kt + c) * 64 + 32 + g * 8];
            s0 = __builtin_amdgcn_mfma_f32_16x16x32_bf16(qf0, ka, s0, 0, 0, 0);
            s0 = __builtin_amdgcn_mfma_f32_16x16x32_bf16(qf1, kb, s0, 0, 0, 0);
        }
        if (p1) {
            bf16x8 ka = *(const bf16x8*)&Kh[(size_t)(kt + 16 + c) * 64 + g * 8];
            bf16x8 kb = *(const bf16x8*)&Kh[(size_t)(kt + 16 + c) * 64 + 32 + g * 8];
            s1 = __builtin_amdgcn_mfma_f32_16x16x32_bf16(qf0, ka, s1, 0, 0, 0);
            s1 = __builtin_amdgcn_mfma_f32_16x16x32_bf16(qf1, kb, s1, 0, 0, 0);
        }
        // causal mask
        if (kt + 15 > qbase) {
#pragma unroll
            for (int r = 0; r < 4; r++)
                if (kt + c > qbase + g * 4 + r) s0[r] = -1e9f;
        }
        if (p1 && kt + 31 > qbase) {
#pragma unroll
            for (int r = 0; r < 4; r++)
                if (kt + 16 + c > qbase + g * 4 + r) s1[r] = -1e9f;
        }
        // online softmax (per q-row, 16-lane groups)
        float sc[4];
#pragma unroll
        for (int r = 0; r < 4; r++) {
            float tm = p1 ? fmaxf(s0[r], s1[r]) : s0[r];
#pragma unroll
            for (int msk = 8; msk >= 1; msk >>= 1) tm = fmaxf(tm, __shfl_xor(tm, msk, 16));
            float mn = fmaxf(m_[r], tm);
            float e0 = expf(s0[r] - mn);
            float e1 = p1 ? expf(s1[r] - mn) : 0.f;
            float rs = e0 + e1;
#pragma unroll
            for (int msk = 8; msk >= 1; msk >>= 1) rs += __shfl_xor(rs, msk, 16);
            float scl = expf(m_[r] - mn);
            l_[r] = l_[r] * scl + rs;
            m_[r] = mn;
            sc[r] = scl;
            Pl[wid][g * 4 + r][c] = f2bf(e0);
            Pl[wid][g * 4 + r][c + 16] = f2bf(e1);
        }
#pragma unroll
        for (int nc = 0; nc < 4; nc++) {
            acc[nc][0] *= sc[0]; acc[nc][1] *= sc[1];
            acc[nc][2] *= sc[2]; acc[nc][3] *= sc[3];
        }
        bf16x8 pf = *(const bf16x8*)&Pl[wid][c][g * 8];
#pragma unroll
        for (int nc = 0; nc < 4; nc++) {
            bf16x8 vf = *(const bf16x8*)&Vh[(size_t)(nc * 16 + c) * LL + kt + g * 8];
            acc[nc] = __builtin_amdgcn_mfma_f32_16x16x32_bf16(pf, vf, acc[nc], 0, 0, 0);
        }
    }
    // epilogue: Out (B,L,C) bf16
    int b = bh >> 4, h = bh & 15;
#pragma unroll
    for (int r = 0; r < 4; r++) {
        float inv = 1.f / l_[r];
        int q = qbase + g * 4 + r;
        size_t ob = ((size_t)b * LL + q) * CC + h * 64;
#pragma unroll
        for (int nc = 0; nc < 4; nc++) Out[ob + nc * 16 + c] = f2bf(acc[nc][r] * inv);
    }
}

extern "C" void kernel_launch(void* const* d_in, const int* in_sizes, int n_in,
                              void* d_out, int out_size, void* d_ws, size_t ws_size,
                              hipStream_t stream) {
    const float* x = (const float*)d_in[0];
    const float* rope = (const float*)d_in[2];
    const float* w1 = (const float*)d_in[3];
    const float* qb = (const float*)d_in[4];
    const float* vb = (const float*)d_in[5];
    const float* w2 = (const float*)d_in[6];
    const float* pb = (const float*)d_in[7];
    const float* smul = (const float*)d_in[8];
    float* out = (float*)d_out;

    char* ws = (char*)d_ws;
    unsigned short* xb = (unsigned short*)(ws + 0);                 // 16777216 B
    unsigned short* w1b = (unsigned short*)(ws + 16777216);         // 6291456
    unsigned short* w2b = (unsigned short*)(ws + 23068672);         // 2097152
    float* biascat = (float*)(ws + 25165824);                       // 12288
    unsigned short* qkvb = (unsigned short*)(ws + 25178112);        // 50331648
    unsigned short* Qb = (unsigned short*)(ws + 75509760);          // 16777216
    unsigned short* Kb = (unsigned short*)(ws + 92286976);          // 16777216
    unsigned short* Vtb = (unsigned short*)(ws + 109064192);        // 16777216
    unsigned short* attb = (unsigned short*)(ws + 125841408);       // 16777216
    if (ws_size < 142618624) return;

    int n4;
    n4 = BB * LL * CC / 4;
    k_f2bf<<<(n4 + 255) / 256, 256, 0, stream>>>((const float4*)x, (ushort4*)xb, n4);
    n4 = 3 * CC * CC / 4;
    k_f2bf<<<(n4 + 255) / 256, 256, 0, stream>>>((const float4*)w1, (ushort4*)w1b, n4);
    n4 = CC * CC / 4;
    k_f2bf<<<(n4 + 255) / 256, 256, 0, stream>>>((const float4*)w2, (ushort4*)w2b, n4);
    k_biascat<<<12, 256, 0, stream>>>(qb, vb, biascat);

    k_gemm_bt<unsigned short><<<(8192 / 128) * (3072 / 128), 256, 0, stream>>>(
        xb, w1b, biascat, qkvb, BB * LL, 3 * CC, CC);

    k_qknorm<<<BB * LL * HH / 4, 256, 0, stream>>>(qkvb, rope, smul, Qb, Kb);
    k_vtrans<<<BB * HH * (LL / 64), 256, 0, stream>>>(qkvb, Vtb);
    k_attn<<<BB * HH * (LL / 64), 256, 0, stream>>>(Qb, Kb, Vtb, attb);

    k_gemm_bt<float><<<(8192 / 128) * (1024 / 128), 256, 0, stream>>>(
        attb, w2b, pb, out, BB * LL, CC, CC);
}

// Round 2
// 354.377 us; speedup vs baseline: 1.7269x; 1.7269x over previous
//
#include <hip/hip_runtime.h>
#include <hip/hip_bf16.h>

#define BB 4
#define LL 2048
#define CC 1024
#define HH 16
#define DD 64
#define HALFD 32

typedef short bf16x8 __attribute__((ext_vector_type(8)));
typedef short bf16x4 __attribute__((ext_vector_type(4)));
typedef float f32x4 __attribute__((ext_vector_type(4)));

#if defined(__has_builtin)
#if __has_builtin(__builtin_amdgcn_mfma_f32_16x16x16bf16_1k)
#define HAVE_MFMA16 1
#endif
#endif

__device__ __forceinline__ float bf2f(unsigned short u) {
    union { unsigned int i; float f; } x; x.i = ((unsigned int)u) << 16; return x.f;
}
__device__ __forceinline__ unsigned short f2bf(float f) {
    union { float f; unsigned int i; } x; x.f = f;
    return (unsigned short)((x.i + 0x7fffu + ((x.i >> 16) & 1u)) >> 16);
}

// ---------------- prep: fp32 -> bf16 ----------------
__global__ void k_f2bf(const float4* __restrict__ in, ushort4* __restrict__ out, int n4) {
    int i = blockIdx.x * blockDim.x + threadIdx.x;
    if (i < n4) {
        float4 v = in[i];
        ushort4 o;
        o.x = f2bf(v.x); o.y = f2bf(v.y); o.z = f2bf(v.z); o.w = f2bf(v.w);
        out[i] = o;
    }
}

__global__ void k_biascat(const float* __restrict__ qb, const float* __restrict__ vb,
                          float* __restrict__ out) {
    int i = blockIdx.x * blockDim.x + threadIdx.x;
    if (i < 3 * CC) out[i] = (i < CC) ? qb[i] : (i < 2 * CC ? 0.f : vb[i - 2 * CC]);
}

// ---------------- GEMM: C[M,N] = A[M,K] * Bt[N,K]^T + bias[N] ----------------
template <typename OutT>
__global__ __launch_bounds__(256) void k_gemm_bt(
    const unsigned short* __restrict__ A, const unsigned short* __restrict__ Bt,
    const float* __restrict__ bias, OutT* __restrict__ Cout, int M, int N, int K) {
    __shared__ unsigned short As[128][40];
    __shared__ unsigned short Bs[128][40];
    int nT = N >> 7;
    int tM = (blockIdx.x / nT) << 7;
    int tN = (blockIdx.x % nT) << 7;
    int t = threadIdx.x;
    int lane = t & 63, wid = t >> 6;
    int wr = (wid >> 1) * 64, wc = (wid & 1) * 64;
    int c = lane & 15, g = lane >> 4;
    f32x4 acc[4][4];
#pragma unroll
    for (int i = 0; i < 4; i++)
#pragma unroll
        for (int j = 0; j < 4; j++) acc[i][j] = (f32x4){0.f, 0.f, 0.f, 0.f};

    for (int k0 = 0; k0 < K; k0 += 32) {
        __syncthreads();
#pragma unroll
        for (int i = t; i < 512; i += 256) {
            int row = i >> 2, ch = (i & 3) << 3;
            *(bf16x8*)&As[row][ch] = *(const bf16x8*)&A[(size_t)(tM + row) * K + k0 + ch];
            *(bf16x8*)&Bs[row][ch] = *(const bf16x8*)&Bt[(size_t)(tN + row) * K + k0 + ch];
        }
        __syncthreads();
        bf16x8 af[4], bfr[4];
#pragma unroll
        for (int fm = 0; fm < 4; fm++) af[fm] = *(const bf16x8*)&As[wr + fm * 16 + c][g * 8];
#pragma unroll
        for (int fn = 0; fn < 4; fn++) bfr[fn] = *(const bf16x8*)&Bs[wc + fn * 16 + c][g * 8];
#pragma unroll
        for (int fm = 0; fm < 4; fm++)
#pragma unroll
            for (int fn = 0; fn < 4; fn++)
                acc[fm][fn] = __builtin_amdgcn_mfma_f32_16x16x32_bf16(af[fm], bfr[fn],
                                                                      acc[fm][fn], 0, 0, 0);
    }
#pragma unroll
    for (int fm = 0; fm < 4; fm++) {
#pragma unroll
        for (int fn = 0; fn < 4; fn++) {
            int col = tN + wc + fn * 16 + c;
            float bv = bias[col];
#pragma unroll
            for (int r = 0; r < 4; r++) {
                int row = tM + wr + fm * 16 + g * 4 + r;
                float v = acc[fm][fn][r] + bv;
                if constexpr (sizeof(OutT) == 2)
                    Cout[(size_t)row * N + col] = f2bf(v);
                else
                    Cout[(size_t)row * N + col] = v;
            }
        }
    }
}

// ---------------- Q/K: l2norm + scale + RoPE, layout (B,H,L,D) bf16 ----------------
__global__ __launch_bounds__(256) void k_qknorm(
    const unsigned short* __restrict__ qkv, const float* __restrict__ rope,
    const float* __restrict__ smul, unsigned short* __restrict__ Q,
    unsigned short* __restrict__ Ko) {
    int wid = threadIdx.x >> 6, lane = threadIdx.x & 63;
    long rowid = (long)blockIdx.x * 4 + wid;  // (b,l,h), h fastest
    int h = rowid & 15;
    long t2 = rowid >> 4;
    int l = t2 & 2047;
    int b = (int)(t2 >> 11);
    size_t base = ((size_t)(b * LL + l) * 3) * CC + h * 64 + lane;
    float q = bf2f(qkv[base]);
    float k = bf2f(qkv[base + CC]);
    float sq = q * q, sk = k * k;
#pragma unroll
    for (int m = 32; m >= 1; m >>= 1) {
        sq += __shfl_xor(sq, m);
        sk += __shfl_xor(sk, m);
    }
    float sm = expf(fminf(smul[h], 4.6051701859880913680f));
    q = q / fmaxf(sqrtf(sq), 1e-12f) * sm;
    k = k / fmaxf(sqrtf(sk), 1e-12f);
    int j = lane >> 1;
    float cs = rope[((size_t)(b * 2) * LL + l) * HALFD + j];
    float sn = rope[((size_t)(b * 2 + 1) * LL + l) * HALFD + j];
    float qp = __shfl_xor(q, 1), kp = __shfl_xor(k, 1);
    float qn = (lane & 1) ? (qp * sn + q * cs) : (q * cs - qp * sn);
    float kn = (lane & 1) ? (kp * sn + k * cs) : (k * cs - kp * sn);
    size_t ob = ((size_t)(b * HH + h) * LL + l) * 64 + lane;
    Q[ob] = f2bf(qn);
    Ko[ob] = f2bf(kn);
}

// ---------------- V transpose: (B,L,H,D) slice of qkv -> Vt (B,H,D,L) bf16 ----------------
__global__ __launch_bounds__(256) void k_vtrans(const unsigned short* __restrict__ qkv,
                                               unsigned short* __restrict__ Vt) {
    __shared__ unsigned short tile[64][65];
    int bid = blockIdx.x;
    int lb = bid & 31;  // L/64
    int bh = bid >> 5;
    int h = bh & 15, b = bh >> 4;
    int t = threadIdx.x;
    for (int i = t; i < 4096; i += 256) {
        int row = i >> 6, dd = i & 63;
        tile[row][dd] = qkv[((size_t)(b * LL + lb * 64 + row) * 3 + 2) * CC + h * 64 + dd];
    }
    __syncthreads();
    for (int i = t; i < 4096; i += 256) {
        int dd = i >> 6, l2 = i & 63;
        Vt[((size_t)bh * 64 + dd) * LL + lb * 64 + l2] = tile[l2][dd];
    }
}

// ---------------- causal flash attention, swapped-QK^T (S^T = K*Q^T) ----------------
// 4 waves/block, each wave 32 q rows (2 q-tiles of 16). KVBLK=32. No LDS.
// S^T tile layout: col(lane&15)=q, row(4*(lane>>4)+reg)=k  ->  P is lane-local per q.
__global__ __launch_bounds__(256) void k_attn(
    const unsigned short* __restrict__ Q, const unsigned short* __restrict__ K,
    const unsigned short* __restrict__ Vt, unsigned short* __restrict__ Out) {
    int lane = threadIdx.x & 63, wid = threadIdx.x >> 6;
    int c = lane & 15, g = lane >> 4;
    int bid = blockIdx.x;
    int bh = bid & 63;
    int strip = 15 - (bid >> 6);  // heavy strips dispatch first
    int qb = strip * 128 + wid * 32;
    const unsigned short* Qh = Q + (size_t)bh * LL * 64;
    const unsigned short* Kh = K + (size_t)bh * LL * 64;
    const unsigned short* Vh = Vt + (size_t)bh * 64 * LL;

    // Q fragments (B-operand): lane holds col=q=qb+qt*16+c, kk(d) = ch*32 + g*8 + e
    bf16x8 qf[2][2];
#pragma unroll
    for (int qt = 0; qt < 2; qt++)
#pragma unroll
        for (int ch = 0; ch < 2; ch++)
            qf[qt][ch] =
                *(const bf16x8*)&Qh[(size_t)(qb + qt * 16 + c) * 64 + ch * 32 + g * 8];

    f32x4 acc[2][4];  // [qt][dtile] of out^T: col=q=c, row=d=4g+r
#pragma unroll
    for (int qt = 0; qt < 2; qt++)
#pragma unroll
        for (int dt = 0; dt < 4; dt++) acc[qt][dt] = (f32x4){0.f, 0.f, 0.f, 0.f};
    float m_[2] = {-1e30f, -1e30f}, l_[2] = {0.f, 0.f};

#ifndef HAVE_MFMA16
    int srcA = 32 * (g & 1) + c;  // fallback transpose sources
    int srcB = srcA + 16;
#endif

    for (int kt = 0; kt < qb + 32; kt += 32) {
        // K fragments (A-operand): lane holds row=k=kt+kt2*16+c, kk(d)=ch*32+g*8+e
        bf16x8 kf[2][2];
#pragma unroll
        for (int kt2 = 0; kt2 < 2; kt2++)
#pragma unroll
            for (int ch = 0; ch < 2; ch++)
                kf[kt2][ch] =
                    *(const bf16x8*)&Kh[(size_t)(kt + kt2 * 16 + c) * 64 + ch * 32 + g * 8];
#ifdef HAVE_MFMA16
        // V^T fragments (A-operand of 16x16x16): row=d=dt*16+c, kk(k)=4g+e
        bf16x4 vf[4][2];
#pragma unroll
        for (int dt = 0; dt < 4; dt++)
#pragma unroll
            for (int kt2 = 0; kt2 < 2; kt2++)
                vf[dt][kt2] =
                    *(const bf16x4*)&Vh[(size_t)(dt * 16 + c) * LL + kt + kt2 * 16 + 4 * g];
#else
        // V^T fragments (A-operand of 16x16x32): row=d, kk(k)=8g+e
        bf16x8 vf8[4];
#pragma unroll
        for (int dt = 0; dt < 4; dt++)
            vf8[dt] = *(const bf16x8*)&Vh[(size_t)(dt * 16 + c) * LL + kt + 8 * g];
#endif
#pragma unroll
        for (int qt = 0; qt < 2; qt++) {
            int qtb = qb + qt * 16;
            int qrow = qtb + c;
            f32x4 s0 = (f32x4){0.f, 0.f, 0.f, 0.f}, s1 = (f32x4){0.f, 0.f, 0.f, 0.f};
            s0 = __builtin_amdgcn_mfma_f32_16x16x32_bf16(kf[0][0], qf[qt][0], s0, 0, 0, 0);
            s0 = __builtin_amdgcn_mfma_f32_16x16x32_bf16(kf[0][1], qf[qt][1], s0, 0, 0, 0);
            s1 = __builtin_amdgcn_mfma_f32_16x16x32_bf16(kf[1][0], qf[qt][0], s1, 0, 0, 0);
            s1 = __builtin_amdgcn_mfma_f32_16x16x32_bf16(kf[1][1], qf[qt][1], s1, 0, 0, 0);
            if (kt + 31 > qtb) {  // only the last k-tile needs masking
#pragma unroll
                for (int r = 0; r < 4; r++) {
                    if (kt + 4 * g + r > qrow) s0[r] = -1e9f;
                    if (kt + 16 + 4 * g + r > qrow) s1[r] = -1e9f;
                }
            }
            // row max over 8 in-lane values, then across the 4 lane-groups
            float tm = fmaxf(fmaxf(fmaxf(s0[0], s0[1]), fmaxf(s0[2], s0[3])),
                             fmaxf(fmaxf(s1[0], s1[1]), fmaxf(s1[2], s1[3])));
            tm = fmaxf(tm, __shfl_xor(tm, 16));
            tm = fmaxf(tm, __shfl_xor(tm, 32));
            float mn = fmaxf(m_[qt], tm);
            float p0[4], p1[4];
            float rs = 0.f;
#pragma unroll
            for (int r = 0; r < 4; r++) {
                p0[r] = __expf(s0[r] - mn);
                p1[r] = __expf(s1[r] - mn);
                rs += p0[r] + p1[r];
            }
            rs += __shfl_xor(rs, 16);
            rs += __shfl_xor(rs, 32);
            float scl = __expf(m_[qt] - mn);
            l_[qt] = l_[qt] * scl + rs;
            m_[qt] = mn;
#pragma unroll
            for (int dt = 0; dt < 4; dt++) {
                acc[qt][dt][0] *= scl; acc[qt][dt][1] *= scl;
                acc[qt][dt][2] *= scl; acc[qt][dt][3] *= scl;
            }
#ifdef HAVE_MFMA16
            // P^T B-frag for 16x16x16: kk=4g+e == exactly p0/p1 register order
            bf16x4 pb0, pb1;
#pragma unroll
            for (int r = 0; r < 4; r++) {
                pb0[r] = (short)f2bf(p0[r]);
                pb1[r] = (short)f2bf(p1[r]);
            }
#pragma unroll
            for (int dt = 0; dt < 4; dt++) {
                acc[qt][dt] =
                    __builtin_amdgcn_mfma_f32_16x16x16bf16_1k(vf[dt][0], pb0, acc[qt][dt], 0, 0, 0);
                acc[qt][dt] =
                    __builtin_amdgcn_mfma_f32_16x16x16bf16_1k(vf[dt][1], pb1, acc[qt][dt], 0, 0, 0);
            }
#else
            // Fallback: build K=32 B-frag (kk=8g+e) via 8 bpermutes.
            // target lane (c,g) needs P^T[8g+e][c]:
            //   words 0,1 from lane (c, 2*(g&1)); words 2,3 from lane (c, 2*(g&1)+1)
            //   register pair (a0,a1)=tile0 if g<2 else (b0,b1)=tile1
            unsigned int A0 = (unsigned int)f2bf(p0[0]) | ((unsigned int)f2bf(p0[1]) << 16);
            unsigned int A1 = (unsigned int)f2bf(p0[2]) | ((unsigned int)f2bf(p0[3]) << 16);
            unsigned int B0 = (unsigned int)f2bf(p1[0]) | ((unsigned int)f2bf(p1[1]) << 16);
            unsigned int B1 = (unsigned int)f2bf(p1[2]) | ((unsigned int)f2bf(p1[3]) << 16);
            int t0a = __shfl((int)A0, srcA), t0b = __shfl((int)B0, srcA);
            int t1a = __shfl((int)A1, srcA), t1b = __shfl((int)B1, srcA);
            int t2a = __shfl((int)A0, srcB), t2b = __shfl((int)B0, srcB);
            int t3a = __shfl((int)A1, srcB), t3b = __shfl((int)B1, srcB);
            union { int w[4]; bf16x8 v; } u;
            bool hi = (g & 2) != 0;
            u.w[0] = hi ? t0b : t0a;
            u.w[1] = hi ? t1b : t1a;
            u.w[2] = hi ? t2b : t2a;
            u.w[3] = hi ? t3b : t3a;
#pragma unroll
            for (int dt = 0; dt < 4; dt++)
                acc[qt][dt] =
                    __builtin_amdgcn_mfma_f32_16x16x32_bf16(vf8[dt], u.v, acc[qt][dt], 0, 0, 0);
#endif
        }
    }
    // epilogue: Out (B,L,C) bf16; lane writes d = dt*16 + 4g + r, q = qb+qt*16+c
    int b = bh >> 4, h = bh & 15;
#pragma unroll
    for (int qt = 0; qt < 2; qt++) {
        float inv = 1.f / l_[qt];
        int qg = qb + qt * 16 + c;
        size_t ob = ((size_t)b * LL + qg) * CC + h * 64;
#pragma unroll
        for (int dt = 0; dt < 4; dt++) {
            ushort4 o;
            o.x = f2bf(acc[qt][dt][0] * inv);
            o.y = f2bf(acc[qt][dt][1] * inv);
            o.z = f2bf(acc[qt][dt][2] * inv);
            o.w = f2bf(acc[qt][dt][3] * inv);
            *(ushort4*)&Out[ob + dt * 16 + 4 * g] = o;
        }
    }
}

extern "C" void kernel_launch(void* const* d_in, const int* in_sizes, int n_in,
                              void* d_out, int out_size, void* d_ws, size_t ws_size,
                              hipStream_t stream) {
    const float* x = (const float*)d_in[0];
    const float* rope = (const float*)d_in[2];
    const float* w1 = (const float*)d_in[3];
    const float* qb = (const float*)d_in[4];
    const float* vb = (const float*)d_in[5];
    const float* w2 = (const float*)d_in[6];
    const float* pb = (const float*)d_in[7];
    const float* smul = (const float*)d_in[8];
    float* out = (float*)d_out;

    char* ws = (char*)d_ws;
    unsigned short* xb = (unsigned short*)(ws + 0);                 // 16777216 B
    unsigned short* w1b = (unsigned short*)(ws + 16777216);         // 6291456
    unsigned short* w2b = (unsigned short*)(ws + 23068672);         // 2097152
    float* biascat = (float*)(ws + 25165824);                       // 12288
    unsigned short* qkvb = (unsigned short*)(ws + 25178112);        // 50331648
    unsigned short* Qb = (unsigned short*)(ws + 75509760);          // 16777216
    unsigned short* Kb = (unsigned short*)(ws + 92286976);          // 16777216
    unsigned short* Vtb = (unsigned short*)(ws + 109064192);        // 16777216
    unsigned short* attb = (unsigned short*)(ws + 125841408);       // 16777216
    if (ws_size < 142618624) return;

    int n4;
    n4 = BB * LL * CC / 4;
    k_f2bf<<<(n4 + 255) / 256, 256, 0, stream>>>((const float4*)x, (ushort4*)xb, n4);
    n4 = 3 * CC * CC / 4;
    k_f2bf<<<(n4 + 255) / 256, 256, 0, stream>>>((const float4*)w1, (ushort4*)w1b, n4);
    n4 = CC * CC / 4;
    k_f2bf<<<(n4 + 255) / 256, 256, 0, stream>>>((const float4*)w2, (ushort4*)w2b, n4);
    k_biascat<<<12, 256, 0, stream>>>(qb, vb, biascat);

    k_gemm_bt<unsigned short><<<(8192 / 128) * (3072 / 128), 256, 0, stream>>>(
        xb, w1b, biascat, qkvb, BB * LL, 3 * CC, CC);

    k_qknorm<<<BB * LL * HH / 4, 256, 0, stream>>>(qkvb, rope, smul, Qb, Kb);
    k_vtrans<<<BB * HH * (LL / 64), 256, 0, stream>>>(qkvb, Vtb);
    k_attn<<<64 * 16, 256, 0, stream>>>(Qb, Kb, Vtb, attb);

    k_gemm_bt<float><<<(8192 / 128) * (1024 / 128), 256, 0, stream>>>(
        attb, w2b, pb, out, BB * LL, CC, CC);
}

// Round 3
// 347.826 us; speedup vs baseline: 1.7594x; 1.0188x over previous
//
#include <hip/hip_runtime.h>
#include <hip/hip_bf16.h>

#define BB 4
#define LL 2048
#define CC 1024
#define HH 16
#define DD 64
#define HALFD 32

typedef short bf16x8 __attribute__((ext_vector_type(8)));
typedef short bf16x4 __attribute__((ext_vector_type(4)));
typedef float f32x4 __attribute__((ext_vector_type(4)));

#if defined(__has_builtin)
#if __has_builtin(__builtin_amdgcn_mfma_f32_16x16x16bf16_1k)
#define HAVE_MFMA16 1
#endif
#endif

__device__ __forceinline__ float bf2f(unsigned short u) {
    union { unsigned int i; float f; } x; x.i = ((unsigned int)u) << 16; return x.f;
}
__device__ __forceinline__ unsigned short f2bf(float f) {
    union { float f; unsigned int i; } x; x.f = f;
    return (unsigned short)((x.i + 0x7fffu + ((x.i >> 16) & 1u)) >> 16);
}
__device__ __forceinline__ void gload_lds16(const void* g, void* l) {
    __builtin_amdgcn_global_load_lds(
        (const __attribute__((address_space(1))) unsigned int*)g,
        (__attribute__((address_space(3))) unsigned int*)l, 16, 0, 0);
}

// ---------------- prep: fp32 -> bf16 ----------------
__global__ void k_f2bf(const float4* __restrict__ in, ushort4* __restrict__ out, int n4) {
    int i = blockIdx.x * blockDim.x + threadIdx.x;
    if (i < n4) {
        float4 v = in[i];
        ushort4 o;
        o.x = f2bf(v.x); o.y = f2bf(v.y); o.z = f2bf(v.z); o.w = f2bf(v.w);
        out[i] = o;
    }
}

__global__ void k_biascat(const float* __restrict__ qb, const float* __restrict__ vb,
                          float* __restrict__ out) {
    int i = blockIdx.x * blockDim.x + threadIdx.x;
    if (i < 3 * CC) out[i] = (i < CC) ? qb[i] : (i < 2 * CC ? 0.f : vb[i - 2 * CC]);
}

// ---------------- GEMM: C[M,N] = A[M,K] * Bt[N,K]^T + bias[N] ----------------
// 128x128 tile, BK=32, 4 waves, global_load_lds(16B) staging into linear LDS (m97).
template <typename OutT>
__global__ __launch_bounds__(256) void k_gemm_bt(
    const unsigned short* __restrict__ A, const unsigned short* __restrict__ Bt,
    const float* __restrict__ bias, OutT* __restrict__ Cout, int M, int N, int K) {
    __shared__ unsigned short As[128][32];
    __shared__ unsigned short Bs[128][32];
    int nT = N >> 7;
    int tM = (blockIdx.x / nT) << 7;
    int tN = (blockIdx.x % nT) << 7;
    int t = threadIdx.x;
    int lane = t & 63, wid = t >> 6;
    int wr = (wid >> 1) * 64, wc = (wid & 1) * 64;
    int c = lane & 15, g = lane >> 4;

    // staging: wave wid covers rows [wid*32, wid*32+32) of As and Bs.
    // DMA writes LDS base + lane*16B -> row wid*32 + chunk*16 + lane/4, col (lane&3)*8.
    const unsigned short* gA = A + (size_t)(tM + wid * 32 + (lane >> 2)) * K + (lane & 3) * 8;
    const unsigned short* gB = Bt + (size_t)(tN + wid * 32 + (lane >> 2)) * K + (lane & 3) * 8;
    unsigned short* lA0 = &As[wid * 32][0];
    unsigned short* lA1 = &As[wid * 32 + 16][0];
    unsigned short* lB0 = &Bs[wid * 32][0];
    unsigned short* lB1 = &Bs[wid * 32 + 16][0];
    size_t r16 = (size_t)16 * K;

    f32x4 acc[4][4];
#pragma unroll
    for (int i = 0; i < 4; i++)
#pragma unroll
        for (int j = 0; j < 4; j++) acc[i][j] = (f32x4){0.f, 0.f, 0.f, 0.f};

    for (int k0 = 0; k0 < K; k0 += 32) {
        __syncthreads();
        gload_lds16(gA + k0, lA0);
        gload_lds16(gA + k0 + r16, lA1);
        gload_lds16(gB + k0, lB0);
        gload_lds16(gB + k0 + r16, lB1);
        __syncthreads();
        bf16x8 af[4], bfr[4];
#pragma unroll
        for (int fm = 0; fm < 4; fm++) af[fm] = *(const bf16x8*)&As[wr + fm * 16 + c][g * 8];
#pragma unroll
        for (int fn = 0; fn < 4; fn++) bfr[fn] = *(const bf16x8*)&Bs[wc + fn * 16 + c][g * 8];
#pragma unroll
        for (int fm = 0; fm < 4; fm++)
#pragma unroll
            for (int fn = 0; fn < 4; fn++)
                acc[fm][fn] = __builtin_amdgcn_mfma_f32_16x16x32_bf16(af[fm], bfr[fn],
                                                                      acc[fm][fn], 0, 0, 0);
    }
#pragma unroll
    for (int fm = 0; fm < 4; fm++) {
#pragma unroll
        for (int fn = 0; fn < 4; fn++) {
            int col = tN + wc + fn * 16 + c;
            float bv = bias[col];
#pragma unroll
            for (int r = 0; r < 4; r++) {
                int row = tM + wr + fm * 16 + g * 4 + r;
                float v = acc[fm][fn][r] + bv;
                if constexpr (sizeof(OutT) == 2)
                    Cout[(size_t)row * N + col] = f2bf(v);
                else
                    Cout[(size_t)row * N + col] = v;
            }
        }
    }
}

// ---------------- Q/K: l2norm + scale + RoPE, layout (B,H,L,D) bf16 ----------------
__global__ __launch_bounds__(256) void k_qknorm(
    const unsigned short* __restrict__ qkv, const float* __restrict__ rope,
    const float* __restrict__ smul, unsigned short* __restrict__ Q,
    unsigned short* __restrict__ Ko) {
    int wid = threadIdx.x >> 6, lane = threadIdx.x & 63;
    long rowid = (long)blockIdx.x * 4 + wid;  // (b,l,h), h fastest
    int h = rowid & 15;
    long t2 = rowid >> 4;
    int l = t2 & 2047;
    int b = (int)(t2 >> 11);
    size_t base = ((size_t)(b * LL + l) * 3) * CC + h * 64 + lane;
    float q = bf2f(qkv[base]);
    float k = bf2f(qkv[base + CC]);
    float sq = q * q, sk = k * k;
#pragma unroll
    for (int m = 32; m >= 1; m >>= 1) {
        sq += __shfl_xor(sq, m);
        sk += __shfl_xor(sk, m);
    }
    float sm = expf(fminf(smul[h], 4.6051701859880913680f));
    q = q / fmaxf(sqrtf(sq), 1e-12f) * sm;
    k = k / fmaxf(sqrtf(sk), 1e-12f);
    int j = lane >> 1;
    float cs = rope[((size_t)(b * 2) * LL + l) * HALFD + j];
    float sn = rope[((size_t)(b * 2 + 1) * LL + l) * HALFD + j];
    float qp = __shfl_xor(q, 1), kp = __shfl_xor(k, 1);
    float qn = (lane & 1) ? (qp * sn + q * cs) : (q * cs - qp * sn);
    float kn = (lane & 1) ? (kp * sn + k * cs) : (k * cs - kp * sn);
    size_t ob = ((size_t)(b * HH + h) * LL + l) * 64 + lane;
    Q[ob] = f2bf(qn);
    Ko[ob] = f2bf(kn);
}

// ---------------- V transpose: (B,L,H,D) slice of qkv -> Vt (B,H,D,L) bf16 ----------------
__global__ __launch_bounds__(256) void k_vtrans(const unsigned short* __restrict__ qkv,
                                               unsigned short* __restrict__ Vt) {
    __shared__ unsigned short tile[64][65];
    int bid = blockIdx.x;
    int lb = bid & 31;  // L/64
    int bh = bid >> 5;
    int h = bh & 15, b = bh >> 4;
    int t = threadIdx.x;
    for (int i = t; i < 4096; i += 256) {
        int row = i >> 6, dd = i & 63;
        tile[row][dd] = qkv[((size_t)(b * LL + lb * 64 + row) * 3 + 2) * CC + h * 64 + dd];
    }
    __syncthreads();
    for (int i = t; i < 4096; i += 256) {
        int dd = i >> 6, l2 = i & 63;
        Vt[((size_t)bh * 64 + dd) * LL + lb * 64 + l2] = tile[l2][dd];
    }
}

// ---------------- causal flash attention, swapped-QK^T, KVBLK=64, defer-max ----------------
// 4 waves/block, each wave 32 q rows (2 q-tiles of 16). No LDS.
// S^T layout: col(lane&15)=q, row(4*(lane>>4)+reg)=k  ->  P lane-local per q-row.
__global__ __launch_bounds__(256) void k_attn(
    const unsigned short* __restrict__ Q, const unsigned short* __restrict__ K,
    const unsigned short* __restrict__ Vt, unsigned short* __restrict__ Out) {
    int lane = threadIdx.x & 63, wid = threadIdx.x >> 6;
    int c = lane & 15, g = lane >> 4;
    int bid = blockIdx.x;
    int bh = bid & 63;
    int strip = 15 - (bid >> 6);  // heavy strips dispatch first
    int qb = strip * 128 + wid * 32;
    const unsigned short* Qh = Q + (size_t)bh * LL * 64;
    const unsigned short* Kh = K + (size_t)bh * LL * 64;
    const unsigned short* Vh = Vt + (size_t)bh * 64 * LL;

    bf16x8 qf[2][2];
#pragma unroll
    for (int qt = 0; qt < 2; qt++)
#pragma unroll
        for (int ch = 0; ch < 2; ch++)
            qf[qt][ch] =
                *(const bf16x8*)&Qh[(size_t)(qb + qt * 16 + c) * 64 + ch * 32 + g * 8];

    f32x4 acc[2][4];  // [qt][dtile] of out^T: col=q=c, row=d=4g+r
#pragma unroll
    for (int qt = 0; qt < 2; qt++)
#pragma unroll
        for (int dt = 0; dt < 4; dt++) acc[qt][dt] = (f32x4){0.f, 0.f, 0.f, 0.f};
    float m_[2] = {-1e30f, -1e30f}, l_[2] = {0.f, 0.f};

#ifndef HAVE_MFMA16
    int srcA = 32 * (g & 1) + c;
    int srcB = srcA + 16;
#endif

    for (int kt = 0; kt < qb + 32; kt += 64) {
        bf16x8 kf[4][2];
#pragma unroll
        for (int kt2 = 0; kt2 < 4; kt2++)
#pragma unroll
            for (int ch = 0; ch < 2; ch++)
                kf[kt2][ch] =
                    *(const bf16x8*)&Kh[(size_t)(kt + kt2 * 16 + c) * 64 + ch * 32 + g * 8];
#ifdef HAVE_MFMA16
        bf16x4 vf[4][4];  // [dt][kt2]: row=d=dt*16+c, kk(k)=4g+e
#pragma unroll
        for (int dt = 0; dt < 4; dt++)
#pragma unroll
            for (int kt2 = 0; kt2 < 4; kt2++)
                vf[dt][kt2] =
                    *(const bf16x4*)&Vh[(size_t)(dt * 16 + c) * LL + kt + kt2 * 16 + 4 * g];
#else
        bf16x8 vf8[4][2];  // [dt][half]: kk(k)=8g+e within 32-half
#pragma unroll
        for (int dt = 0; dt < 4; dt++)
#pragma unroll
            for (int hf = 0; hf < 2; hf++)
                vf8[dt][hf] =
                    *(const bf16x8*)&Vh[(size_t)(dt * 16 + c) * LL + kt + hf * 32 + 8 * g];
#endif
#pragma unroll
        for (int qt = 0; qt < 2; qt++) {
            int qtb = qb + qt * 16;
            int qrow = qtb + c;
            f32x4 s[4];
#pragma unroll
            for (int kt2 = 0; kt2 < 4; kt2++) {
                s[kt2] = (f32x4){0.f, 0.f, 0.f, 0.f};
                s[kt2] = __builtin_amdgcn_mfma_f32_16x16x32_bf16(kf[kt2][0], qf[qt][0],
                                                                 s[kt2], 0, 0, 0);
                s[kt2] = __builtin_amdgcn_mfma_f32_16x16x32_bf16(kf[kt2][1], qf[qt][1],
                                                                 s[kt2], 0, 0, 0);
            }
            if (kt + 63 > qtb) {
#pragma unroll
                for (int kt2 = 0; kt2 < 4; kt2++) {
                    if (kt + kt2 * 16 + 15 > qtb) {
#pragma unroll
                        for (int r = 0; r < 4; r++)
                            if (kt + kt2 * 16 + 4 * g + r > qrow) s[kt2][r] = -1e9f;
                    }
                }
            }
            // tile max over 16 in-lane values + cross-group
            float tm = fmaxf(fmaxf(fmaxf(s[0][0], s[0][1]), fmaxf(s[0][2], s[0][3])),
                             fmaxf(fmaxf(s[1][0], s[1][1]), fmaxf(s[1][2], s[1][3])));
            float tm2 = fmaxf(fmaxf(fmaxf(s[2][0], s[2][1]), fmaxf(s[2][2], s[2][3])),
                              fmaxf(fmaxf(s[3][0], s[3][1]), fmaxf(s[3][2], s[3][3])));
            tm = fmaxf(tm, tm2);
            tm = fmaxf(tm, __shfl_xor(tm, 16));
            tm = fmaxf(tm, __shfl_xor(tm, 32));
            // defer-max: logits bounded by |sm|<=4 -> after first tile growth <= 8 always
            if (__any(tm > m_[qt] + 8.0f)) {
                float mn = fmaxf(m_[qt], tm);
                float scl = __expf(m_[qt] - mn);
                m_[qt] = mn;
                l_[qt] *= scl;
#pragma unroll
                for (int dt = 0; dt < 4; dt++) {
                    acc[qt][dt][0] *= scl; acc[qt][dt][1] *= scl;
                    acc[qt][dt][2] *= scl; acc[qt][dt][3] *= scl;
                }
            }
            float p[4][4];
            float rs = 0.f;
#pragma unroll
            for (int kt2 = 0; kt2 < 4; kt2++)
#pragma unroll
                for (int r = 0; r < 4; r++) {
                    p[kt2][r] = __expf(s[kt2][r] - m_[qt]);
                    rs += p[kt2][r];
                }
            rs += __shfl_xor(rs, 16);
            rs += __shfl_xor(rs, 32);
            l_[qt] += rs;
#ifdef HAVE_MFMA16
            bf16x4 pb[4];
#pragma unroll
            for (int kt2 = 0; kt2 < 4; kt2++)
#pragma unroll
                for (int r = 0; r < 4; r++) pb[kt2][r] = (short)f2bf(p[kt2][r]);
#pragma unroll
            for (int dt = 0; dt < 4; dt++)
#pragma unroll
                for (int kt2 = 0; kt2 < 4; kt2++)
                    acc[qt][dt] = __builtin_amdgcn_mfma_f32_16x16x16bf16_1k(
                        vf[dt][kt2], pb[kt2], acc[qt][dt], 0, 0, 0);
#else
#pragma unroll
            for (int hf = 0; hf < 2; hf++) {
                unsigned int A0 = (unsigned int)f2bf(p[2 * hf][0]) |
                                  ((unsigned int)f2bf(p[2 * hf][1]) << 16);
                unsigned int A1 = (unsigned int)f2bf(p[2 * hf][2]) |
                                  ((unsigned int)f2bf(p[2 * hf][3]) << 16);
                unsigned int B0 = (unsigned int)f2bf(p[2 * hf + 1][0]) |
                                  ((unsigned int)f2bf(p[2 * hf + 1][1]) << 16);
                unsigned int B1 = (unsigned int)f2bf(p[2 * hf + 1][2]) |
                                  ((unsigned int)f2bf(p[2 * hf + 1][3]) << 16);
                int t0a = __shfl((int)A0, srcA), t0b = __shfl((int)B0, srcA);
                int t1a = __shfl((int)A1, srcA), t1b = __shfl((int)B1, srcA);
                int t2a = __shfl((int)A0, srcB), t2b = __shfl((int)B0, srcB);
                int t3a = __shfl((int)A1, srcB), t3b = __shfl((int)B1, srcB);
                union { int w[4]; bf16x8 v; } u;
                bool hi = (g & 2) != 0;
                u.w[0] = hi ? t0b : t0a;
                u.w[1] = hi ? t1b : t1a;
                u.w[2] = hi ? t2b : t2a;
                u.w[3] = hi ? t3b : t3a;
#pragma unroll
                for (int dt = 0; dt < 4; dt++)
                    acc[qt][dt] = __builtin_amdgcn_mfma_f32_16x16x32_bf16(
                        vf8[dt][hf], u.v, acc[qt][dt], 0, 0, 0);
            }
#endif
        }
    }
    // epilogue: Out (B,L,C) bf16; lane writes d = dt*16 + 4g + r, q = qb+qt*16+c
    int b = bh >> 4, h = bh & 15;
#pragma unroll
    for (int qt = 0; qt < 2; qt++) {
        float inv = 1.f / l_[qt];
        int qg = qb + qt * 16 + c;
        size_t ob = ((size_t)b * LL + qg) * CC + h * 64;
#pragma unroll
        for (int dt = 0; dt < 4; dt++) {
            ushort4 o;
            o.x = f2bf(acc[qt][dt][0] * inv);
            o.y = f2bf(acc[qt][dt][1] * inv);
            o.z = f2bf(acc[qt][dt][2] * inv);
            o.w = f2bf(acc[qt][dt][3] * inv);
            *(ushort4*)&Out[ob + dt * 16 + 4 * g] = o;
        }
    }
}

extern "C" void kernel_launch(void* const* d_in, const int* in_sizes, int n_in,
                              void* d_out, int out_size, void* d_ws, size_t ws_size,
                              hipStream_t stream) {
    const float* x = (const float*)d_in[0];
    const float* rope = (const float*)d_in[2];
    const float* w1 = (const float*)d_in[3];
    const float* qb = (const float*)d_in[4];
    const float* vb = (const float*)d_in[5];
    const float* w2 = (const float*)d_in[6];
    const float* pb = (const float*)d_in[7];
    const float* smul = (const float*)d_in[8];
    float* out = (float*)d_out;

    char* ws = (char*)d_ws;
    unsigned short* xb = (unsigned short*)(ws + 0);                 // 16777216 B
    unsigned short* w1b = (unsigned short*)(ws + 16777216);         // 6291456
    unsigned short* w2b = (unsigned short*)(ws + 23068672);         // 2097152
    float* biascat = (float*)(ws + 25165824);                       // 12288
    unsigned short* qkvb = (unsigned short*)(ws + 25178112);        // 50331648
    unsigned short* Qb = (unsigned short*)(ws + 75509760);          // 16777216
    unsigned short* Kb = (unsigned short*)(ws + 92286976);          // 16777216
    unsigned short* Vtb = (unsigned short*)(ws + 109064192);        // 16777216
    unsigned short* attb = (unsigned short*)(ws + 125841408);       // 16777216
    if (ws_size < 142618624) return;

    int n4;
    n4 = BB * LL * CC / 4;
    k_f2bf<<<(n4 + 255) / 256, 256, 0, stream>>>((const float4*)x, (ushort4*)xb, n4);
    n4 = 3 * CC * CC / 4;
    k_f2bf<<<(n4 + 255) / 256, 256, 0, stream>>>((const float4*)w1, (ushort4*)w1b, n4);
    n4 = CC * CC / 4;
    k_f2bf<<<(n4 + 255) / 256, 256, 0, stream>>>((const float4*)w2, (ushort4*)w2b, n4);
    k_biascat<<<12, 256, 0, stream>>>(qb, vb, biascat);

    k_gemm_bt<unsigned short><<<(8192 / 128) * (3072 / 128), 256, 0, stream>>>(
        xb, w1b, biascat, qkvb, BB * LL, 3 * CC, CC);

    k_qknorm<<<BB * LL * HH / 4, 256, 0, stream>>>(qkvb, rope, smul, Qb, Kb);
    k_vtrans<<<BB * HH * (LL / 64), 256, 0, stream>>>(qkvb, Vtb);
    k_attn<<<64 * 16, 256, 0, stream>>>(Qb, Kb, Vtb, attb);

    k_gemm_bt<float><<<(8192 / 128) * (1024 / 128), 256, 0, stream>>>(
        attb, w2b, pb, out, BB * LL, CC, CC);
}